// Round 3
// baseline (304.339 us; speedup 1.0000x reference)
//
#include <hip/hip_runtime.h>
#include <stdint.h>

#define D_MODEL 1024
#define D_FF    4096
#define NROWS   8192   // 4 * 2048

typedef __attribute__((ext_vector_type(4))) float f32x4;
typedef __attribute__((ext_vector_type(8))) short short8;

__device__ __forceinline__ unsigned short f2bf(float f) {
  unsigned u = __float_as_uint(f);
  u += 0x7fffu + ((u >> 16) & 1u);   // round-to-nearest-even
  return (unsigned short)(u >> 16);
}

// ---------------- LayerNorm (fp32 in) -> bf16 out ----------------
__global__ __launch_bounds__(256) void ln_bf16_kernel(
    const float* __restrict__ x, const float* __restrict__ lnw,
    const float* __restrict__ lnb, unsigned short* __restrict__ y) {
  const int row = blockIdx.x;
  const int t = threadIdx.x;
  const int w = t >> 6, l = t & 63;
  const float4* xr = (const float4*)(x + (size_t)row * D_MODEL);
  float4 v = xr[t];
  float s  = v.x + v.y + v.z + v.w;
  float s2 = v.x * v.x + v.y * v.y + v.z * v.z + v.w * v.w;
#pragma unroll
  for (int o = 32; o >= 1; o >>= 1) {
    s  += __shfl_xor(s, o);
    s2 += __shfl_xor(s2, o);
  }
  __shared__ float red[8];
  if (l == 0) { red[w] = s; red[4 + w] = s2; }
  __syncthreads();
  s  = red[0] + red[1] + red[2] + red[3];
  s2 = red[4] + red[5] + red[6] + red[7];
  const float mu  = s * (1.0f / D_MODEL);
  const float var = s2 * (1.0f / D_MODEL) - mu * mu;
  const float rs  = rsqrtf(var + 1e-5f);
  float4 wv = ((const float4*)lnw)[t];
  float4 bv = ((const float4*)lnb)[t];
  ushort4 o4;
  o4.x = f2bf((v.x - mu) * rs * wv.x + bv.x);
  o4.y = f2bf((v.y - mu) * rs * wv.y + bv.y);
  o4.z = f2bf((v.z - mu) * rs * wv.z + bv.z);
  o4.w = f2bf((v.w - mu) * rs * wv.w + bv.w);
  *(ushort4*)(y + (size_t)row * D_MODEL + t * 4) = o4;
}

// ------------- transpose + fp32->bf16 convert: dst[C][R] = src[R][C] -------------
__global__ __launch_bounds__(256) void transpose_f32_bf16(
    const float* __restrict__ src, unsigned short* __restrict__ dst,
    int R, int C) {
  __shared__ float tile[32][33];
  const int tx = threadIdx.x;  // 0..31
  const int ty = threadIdx.y;  // 0..7
  const int r0 = blockIdx.y * 32, c0 = blockIdx.x * 32;
#pragma unroll
  for (int i = 0; i < 32; i += 8)
    tile[ty + i][tx] = src[(size_t)(r0 + ty + i) * C + (c0 + tx)];
  __syncthreads();
#pragma unroll
  for (int i = 0; i < 32; i += 8)
    dst[(size_t)(c0 + ty + i) * R + (r0 + tx)] = f2bf(tile[tx][ty + i]);
}

// ---------------- bf16 GEMM, C = A @ Bt^T (+bias, opt ReLU) ----------------
// A:  [M][K] bf16 bits, row-major;  Bt: [N][K] bf16 bits, row-major.
// 128x128 tile, BK=64, 4 waves (2x2), 64x64/wave = 4x4 frags of 16x16,
// global_load_lds width 16 into linear LDS.
// PREFETCH=1: explicit LDS double-buffer, loads in flight across a single raw
// s_barrier per K-tile (T3-minimum recipe); for grid-starved shapes (2 blk/CU).
// PREFETCH=0: plain 2-barrier loop (3 blk/CU implicit overlap per m114).
// Both: XCD-chunked blockIdx swizzle (T1; grids here are multiples of 8).
template <int RELU, int BF16OUT, int PREFETCH>
__global__ __launch_bounds__(256, PREFETCH ? 2 : 3) void gemm_bt(
    const unsigned short* __restrict__ A, const unsigned short* __restrict__ Bt,
    const float* __restrict__ bias, unsigned short* __restrict__ Cb,
    float* __restrict__ Cf, int M, int N, int K) {
  constexpr int BM = 128, BN = 128, BK = 64;
  constexpr int NBUF = PREFETCH ? 2 : 1;
  __shared__ short lA[NBUF * BM * BK];
  __shared__ short lB[NBUF * BN * BK];
  const int t = threadIdx.x;
  const int w = t >> 6, l = t & 63;

  // T1: XCD-chunked bijective remap (nwg % 8 == 0 for both our grids).
  const int gx = gridDim.x;
  const int nwg = gx * gridDim.y;
  int id = blockIdx.y * gx + blockIdx.x;
  id = (id & 7) * (nwg >> 3) + (id >> 3);
  const int bn0 = (id % gx) * BN;
  const int bm0 = (id / gx) * BM;

  const int wm = (w >> 1) * 64, wn = (w & 1) * 64;

  f32x4 acc[4][4];
  const f32x4 zero = {0.f, 0.f, 0.f, 0.f};
#pragma unroll
  for (int i = 0; i < 4; ++i)
#pragma unroll
    for (int j = 0; j < 4; ++j) acc[i][j] = zero;

  // Stage K-tile kt into buffer buf. 16 chunks of (64 lanes x 16B) per matrix;
  // wave w covers chunks {w, w+4, w+8, w+12}. LDS dest = uniform base + l*16.
  auto stage = [&](int buf, int kt) {
    const int k0 = kt * BK;
    const int bo = buf * BM * BK;
#pragma unroll
    for (int p = 0; p < 4; ++p) {
      const int eb = (((p * 4 + w) * 64) + l) * 8;  // element offset in tile
      const int r = eb >> 6, c = eb & 63;
      __builtin_amdgcn_global_load_lds(
          (const __attribute__((address_space(1))) void*)(A + (size_t)(bm0 + r) * K + (k0 + c)),
          (__attribute__((address_space(3))) void*)(&lA[bo + eb]), 16, 0, 0);
      __builtin_amdgcn_global_load_lds(
          (const __attribute__((address_space(1))) void*)(Bt + (size_t)(bn0 + r) * K + (k0 + c)),
          (__attribute__((address_space(3))) void*)(&lB[bo + eb]), 16, 0, 0);
    }
  };

  auto compute = [&](int buf) {
    const short8* pA = (const short8*)&lA[buf * BM * BK];
    const short8* pB = (const short8*)&lB[buf * BN * BK];
#pragma unroll
    for (int kb = 0; kb < 2; ++kb) {
      short8 af[4], bfr[4];
      const int kc = kb * 4 + (l >> 4);  // k-granule (8 bf16 each)
#pragma unroll
      for (int f = 0; f < 4; ++f) {
        af[f]  = pA[(wm + f * 16 + (l & 15)) * 8 + kc];
        bfr[f] = pB[(wn + f * 16 + (l & 15)) * 8 + kc];
      }
#pragma unroll
      for (int fm = 0; fm < 4; ++fm)
#pragma unroll
        for (int fn = 0; fn < 4; ++fn)
          acc[fm][fn] = __builtin_amdgcn_mfma_f32_16x16x32_bf16(
              af[fm], bfr[fn], acc[fm][fn], 0, 0, 0);
    }
  };

  const int nkt = K / BK;
  if (PREFETCH) {
    stage(0, 0);
    asm volatile("s_waitcnt vmcnt(0)" ::: "memory");
    __builtin_amdgcn_s_barrier();
    int cur = 0;
    for (int kt = 0; kt < nkt - 1; ++kt) {
      stage(cur ^ 1, kt + 1);   // next tile's loads fly during compute
      compute(cur);
      asm volatile("s_waitcnt vmcnt(0)" ::: "memory");
      __builtin_amdgcn_s_barrier();   // next buf ready + cur fully read
      cur ^= 1;
    }
    compute(cur);
  } else {
    for (int kt = 0; kt < nkt; ++kt) {
      stage(0, kt);
      __syncthreads();
      compute(0);
      __syncthreads();
    }
  }

  // Epilogue: D(m,n): col = lane&15, row = (lane>>4)*4 + reg (verified m89/m91)
#pragma unroll
  for (int fn = 0; fn < 4; ++fn) {
    const int n = bn0 + wn + fn * 16 + (l & 15);
    const float bv = bias[n];
#pragma unroll
    for (int fm = 0; fm < 4; ++fm) {
      const int mbase = bm0 + wm + fm * 16 + ((l >> 4) * 4);
#pragma unroll
      for (int j = 0; j < 4; ++j) {
        float v = acc[fm][fn][j] + bv;
        if (RELU) v = v > 0.f ? v : 0.f;
        if (BF16OUT) Cb[(size_t)(mbase + j) * N + n] = f2bf(v);
        else         Cf[(size_t)(mbase + j) * N + n] = v;
      }
    }
  }
}

extern "C" void kernel_launch(void* const* d_in, const int* in_sizes, int n_in,
                              void* d_out, int out_size, void* d_ws, size_t ws_size,
                              hipStream_t stream) {
  const float* x   = (const float*)d_in[0];
  const float* lnw = (const float*)d_in[1];
  const float* lnb = (const float*)d_in[2];
  const float* w1  = (const float*)d_in[3];
  const float* b1  = (const float*)d_in[4];
  const float* w2  = (const float*)d_in[5];
  const float* b2  = (const float*)d_in[6];
  float* out = (float*)d_out;

  char* ws = (char*)d_ws;
  unsigned short* x_ln = (unsigned short*)(ws);                      // 16 MB
  unsigned short* w1t  = (unsigned short*)(ws + (16u << 20));        //  8 MB
  unsigned short* w2t  = (unsigned short*)(ws + (24u << 20));        //  8 MB
  unsigned short* h    = (unsigned short*)(ws + (32u << 20));        // 64 MB
  // total workspace use: 96 MB

  ln_bf16_kernel<<<NROWS, 256, 0, stream>>>(x, lnw, lnb, x_ln);
  transpose_f32_bf16<<<dim3(D_FF / 32, D_MODEL / 32), dim3(32, 8), 0, stream>>>(
      w1, w1t, D_MODEL, D_FF);
  transpose_f32_bf16<<<dim3(D_MODEL / 32, D_FF / 32), dim3(32, 8), 0, stream>>>(
      w2, w2t, D_FF, D_MODEL);
  // h = ReLU(x_ln @ w1 + b1), bf16.  2048 blocks (~3/CU): no-prefetch variant.
  gemm_bt<1, 1, 0><<<dim3(D_FF / 128, NROWS / 128), 256, 0, stream>>>(
      x_ln, w1t, b1, h, nullptr, NROWS, D_FF, D_MODEL);
  // out = h @ w2 + b2, fp32.  512 blocks (grid-starved): prefetch variant.
  gemm_bt<0, 0, 1><<<dim3(D_MODEL / 128, NROWS / 128), 256, 0, stream>>>(
      h, w2t, b2, nullptr, out, NROWS, D_MODEL, D_FF);
}

// Round 6
// 277.509 us; speedup vs baseline: 1.0967x; 1.0967x over previous
//
#include <hip/hip_runtime.h>
#include <stdint.h>

#define D_MODEL 1024
#define D_FF    4096
#define NROWS   8192   // 4 * 2048

typedef __attribute__((ext_vector_type(4))) float f32x4;
typedef __attribute__((ext_vector_type(8))) short short8;

__device__ __forceinline__ unsigned short f2bf(float f) {
  unsigned u = __float_as_uint(f);
  u += 0x7fffu + ((u >> 16) & 1u);   // round-to-nearest-even
  return (unsigned short)(u >> 16);
}

template <int N>
__device__ __forceinline__ void wait_vmcnt() {
  asm volatile("s_waitcnt vmcnt(%0)" ::"n"(N) : "memory");
}

// ---------------- LayerNorm (fp32 in) -> bf16 out ----------------
__global__ __launch_bounds__(256) void ln_bf16_kernel(
    const float* __restrict__ x, const float* __restrict__ lnw,
    const float* __restrict__ lnb, unsigned short* __restrict__ y) {
  const int row = blockIdx.x;
  const int t = threadIdx.x;
  const int w = t >> 6, l = t & 63;
  const float4* xr = (const float4*)(x + (size_t)row * D_MODEL);
  float4 v = xr[t];
  float s  = v.x + v.y + v.z + v.w;
  float s2 = v.x * v.x + v.y * v.y + v.z * v.z + v.w * v.w;
#pragma unroll
  for (int o = 32; o >= 1; o >>= 1) {
    s  += __shfl_xor(s, o);
    s2 += __shfl_xor(s2, o);
  }
  __shared__ float red[8];
  if (l == 0) { red[w] = s; red[4 + w] = s2; }
  __syncthreads();
  s  = red[0] + red[1] + red[2] + red[3];
  s2 = red[4] + red[5] + red[6] + red[7];
  const float mu  = s * (1.0f / D_MODEL);
  const float var = s2 * (1.0f / D_MODEL) - mu * mu;
  const float rs  = rsqrtf(var + 1e-5f);
  float4 wv = ((const float4*)lnw)[t];
  float4 bv = ((const float4*)lnb)[t];
  ushort4 o4;
  o4.x = f2bf((v.x - mu) * rs * wv.x + bv.x);
  o4.y = f2bf((v.y - mu) * rs * wv.y + bv.y);
  o4.z = f2bf((v.z - mu) * rs * wv.z + bv.z);
  o4.w = f2bf((v.w - mu) * rs * wv.w + bv.w);
  *(ushort4*)(y + (size_t)row * D_MODEL + t * 4) = o4;
}

// ------------- transpose + fp32->bf16 convert: dst[C][R] = src[R][C] -------------
__global__ __launch_bounds__(256) void transpose_f32_bf16(
    const float* __restrict__ src, unsigned short* __restrict__ dst,
    int R, int C) {
  __shared__ float tile[32][33];
  const int tx = threadIdx.x;  // 0..31
  const int ty = threadIdx.y;  // 0..7
  const int r0 = blockIdx.y * 32, c0 = blockIdx.x * 32;
#pragma unroll
  for (int i = 0; i < 32; i += 8)
    tile[ty + i][tx] = src[(size_t)(r0 + ty + i) * C + (c0 + tx)];
  __syncthreads();
#pragma unroll
  for (int i = 0; i < 32; i += 8)
    dst[(size_t)(c0 + ty + i) * R + (r0 + tx)] = f2bf(tile[tx][ty + i]);
}

// ================== 8-phase 256xBN bf16 GEMM (T2+T3+T4+T5) ==================
// C = A @ Bt^T (+bias, opt ReLU).  A: [M][K] bf16 bits row-major, Bt: [N][K].
// BM=256, BK=64, 2 K-tiles per iteration, 8 waves (2M x 4N), 512 threads.
// Double-buffered LDS at K-tile granularity; each K-tile = 4 half-tiles
// (A-half mq, B-half nq), staged one half-tile per phase via global_load_lds
// (linear LDS dest, inverse-swizzled global source). ds_read slot XOR-swizzle
// (slot ^= row&7) -> conflict-free b128 reads (8 consecutive lanes hit 8
// distinct 16B slots). Counted vmcnt per phase (never 0 in loop); min
// stage->read distance = 5 phases; each phase's wait covers the NEXT phase's
// reads via the barrier chain (ledger verified load-by-load for both LA/LB
// mixes).
//
// Per-iteration schedule (phase: reads buf/quad | stages region <- K-tile):
//  p0: buf0 (0,0) | buf1.B1 <- 2it+1      p4: buf1 (0,0) | buf0.B1 <- 2it+2
//  p1: buf0 (0,1) | buf1.A1 <- 2it+1      p5: buf1 (0,1) | buf0.A1 <- 2it+2
//  p2: buf0 (1,0) | buf0.A0 <- 2it+2      p6: buf1 (1,0) | buf1.A0 <- 2it+3
//  p3: buf0 (1,1) | buf0.B0 <- 2it+2      p7: buf1 (1,1) | buf1.B0 <- 2it+3
template <int BN, int RELU, int BF16OUT>
__global__ __launch_bounds__(512, 2) void gemm8p(
    const unsigned short* __restrict__ A, const unsigned short* __restrict__ Bt,
    const float* __restrict__ bias, unsigned short* __restrict__ Cb,
    float* __restrict__ Cf, int M, int N, int K) {
  constexpr int BM = 256;
  constexpr int FN = BN / 64;        // n-frags per wave (4 or 2)
  constexpr int FNH = FN / 2;        // n-frags per quadrant (2 or 1)
  constexpr int LA = 2;              // global_load_lds per thread per A-half
  constexpr int LB = BN / 128;       // ... per B-half (2 or 1)
  constexpr int AH = 128 * 64;       // shorts per A-half
  constexpr int BH = (BN / 2) * 64;  // shorts per B-half
  constexpr int BUFSZ = 2 * AH + 2 * BH;  // shorts per K-tile buffer
  constexpr int RPW = BN / 8;        // B rows per wave per half (32 or 16)
  constexpr int WTN = BN / 4;        // wave n-extent
  constexpr int NW_A = 2 * LA + LB;  // vmcnt at phases 0,3,4,7
  constexpr int NW_B = LA + 2 * LB;  // vmcnt at phases 1,2,5,6

  __shared__ short lds[2 * BUFSZ];

  const int t = threadIdx.x;
  const int w = t >> 6, l = t & 63;
  const int wm = w >> 2, wn = w & 3;
  const int lr = l & 15, lg = l >> 4, l7 = l & 7;
  const int wm64 = wm * 64, wnr = wn * RPW;

  // T1: XCD-chunked bijective remap (nwg % 8 == 0 for both grids).
  const int gx = gridDim.x;
  const int nwg = gx * gridDim.y;
  int id = blockIdx.y * gx + blockIdx.x;
  id = (id & 7) * (nwg >> 3) + (id >> 3);
  const int bn0 = (id % gx) * BN;
  const int bm0 = (id / gx) * BM;

  f32x4 acc[8][FN];
#pragma unroll
  for (int i = 0; i < 8; ++i)
#pragma unroll
    for (int j = 0; j < FN; ++j) acc[i][j] = (f32x4){0.f, 0.f, 0.f, 0.f};

  // Stage A-half mq of K-tile kt into buffer buf. Linear LDS dest
  // (uniform base + lane*16); global source pre-swizzled (slot ^ row&7).
  auto stageA = [&](int buf, int mq, int kt) {
#pragma unroll
    for (int i = 0; i < LA; ++i) {
      const int idx = i * 512 + t;
      const int r = idx >> 3;                      // row within half [0,128)
      const int sl = (idx & 7) ^ (r & 7);          // source k-slot
      const int grow = bm0 + ((r >> 6) << 7) + (mq << 6) + (r & 63);
      __builtin_amdgcn_global_load_lds(
          (const __attribute__((address_space(1))) void*)(A + (size_t)grow * K + kt * 64 + sl * 8),
          (__attribute__((address_space(3))) void*)(&lds[buf * BUFSZ + mq * AH + idx * 8]),
          16, 0, 0);
    }
  };
  auto stageB = [&](int buf, int nq, int kt) {
#pragma unroll
    for (int i = 0; i < LB; ++i) {
      const int idx = i * 512 + t;
      const int r = idx >> 3;                      // row within half [0,BN/2)
      const int sl = (idx & 7) ^ (r & 7);
      const int grow = bn0 + (r / RPW) * WTN + nq * RPW + (r % RPW);
      __builtin_amdgcn_global_load_lds(
          (const __attribute__((address_space(1))) void*)(Bt + (size_t)grow * K + kt * 64 + sl * 8),
          (__attribute__((address_space(3))) void*)(&lds[buf * BUFSZ + 2 * AH + nq * BH + idx * 8]),
          16, 0, 0);
    }
  };

// One phase: counted vmcnt; ds_read quadrant (swizzled); issue 1 half-tile
// stage; barrier; lgkmcnt(0)+sched_barrier (rule 18); setprio'd MFMA cluster;
// sched_barrier (pin stages/reads below barrier2); barrier.
#define PHASE(MQ, NQ, BUFR, NWAIT, STAGESTMT)                                  \
  {                                                                            \
    wait_vmcnt<NWAIT>();                                                       \
    short8 af[2][4];                                                           \
    short8 bv[2][FNH];                                                         \
    _Pragma("unroll") for (int ks = 0; ks < 2; ++ks) {                         \
      const int sw = (ks << 2) | lg;                                           \
      _Pragma("unroll") for (int f = 0; f < 4; ++f)                            \
        af[ks][f] = *(const short8*)&lds[(BUFR) * BUFSZ + (MQ) * AH +          \
                                         (wm64 + f * 16 + lr) * 64 +           \
                                         ((sw ^ l7) << 3)];                    \
      _Pragma("unroll") for (int f = 0; f < FNH; ++f)                          \
        bv[ks][f] = *(const short8*)&lds[(BUFR) * BUFSZ + 2 * AH + (NQ) * BH + \
                                         (wnr + f * 16 + lr) * 64 +            \
                                         ((sw ^ l7) << 3)];                    \
    }                                                                          \
    STAGESTMT;                                                                 \
    __builtin_amdgcn_s_barrier();                                              \
    asm volatile("s_waitcnt lgkmcnt(0)" ::: "memory");                         \
    __builtin_amdgcn_sched_barrier(0);                                         \
    __builtin_amdgcn_s_setprio(1);                                             \
    _Pragma("unroll") for (int ks = 0; ks < 2; ++ks)                           \
      _Pragma("unroll") for (int f = 0; f < 4; ++f)                            \
        _Pragma("unroll") for (int g = 0; g < FNH; ++g)                        \
          acc[(MQ) * 4 + f][(NQ) * FNH + g] =                                  \
              __builtin_amdgcn_mfma_f32_16x16x32_bf16(                         \
                  af[ks][f], bv[ks][g], acc[(MQ) * 4 + f][(NQ) * FNH + g],     \
                  0, 0, 0);                                                    \
    __builtin_amdgcn_s_setprio(0);                                             \
    __builtin_amdgcn_sched_barrier(0);                                         \
    __builtin_amdgcn_s_barrier();                                              \
  }

  const int KT_MAX = (K >> 6) - 1;
  const int NIT = K >> 7;

  // Prologue: buf0 K-tile 0 (A0,B0,B1,A1) + buf1 K-tile 1 (A0,B0).
  stageA(0, 0, 0);
  stageB(0, 0, 0);
  stageB(0, 1, 0);
  stageA(0, 1, 0);
  stageA(1, 0, 1);
  stageB(1, 0, 1);
  wait_vmcnt<2 * LA + 2 * LB>();   // A0,B0 of buf0 landed (all waves at barrier)
  __builtin_amdgcn_s_barrier();

  for (int it = 0; it < NIT; ++it) {
    const int k1 = 2 * it + 1;
    int k2 = 2 * it + 2; k2 = k2 > KT_MAX ? KT_MAX : k2;
    int k3 = 2 * it + 3; k3 = k3 > KT_MAX ? KT_MAX : k3;
    PHASE(0, 0, 0, NW_A, stageB(1, 1, k1));
    PHASE(0, 1, 0, NW_B, stageA(1, 1, k1));
    PHASE(1, 0, 0, NW_B, stageA(0, 0, k2));
    PHASE(1, 1, 0, NW_A, stageB(0, 0, k2));
    PHASE(0, 0, 1, NW_A, stageB(0, 1, k2));
    PHASE(0, 1, 1, NW_B, stageA(0, 1, k2));
    PHASE(1, 0, 1, NW_B, stageA(1, 0, k3));
    PHASE(1, 1, 1, NW_A, stageB(1, 0, k3));
  }
#undef PHASE
  asm volatile("s_waitcnt vmcnt(0)" ::: "memory");  // drain tail stages

  // Epilogue: D(m,n): col = lane&15, row = (lane>>4)*4 + reg (verified layout)
#pragma unroll
  for (int fn = 0; fn < FN; ++fn) {
    const int col = bn0 + wn * WTN + fn * 16 + lr;
    const float bvs = bias[col];
#pragma unroll
    for (int fm = 0; fm < 8; ++fm) {
      const int rb = bm0 + wm * 128 + fm * 16 + lg * 4;
#pragma unroll
      for (int j = 0; j < 4; ++j) {
        float v = acc[fm][fn][j] + bvs;
        if (RELU) v = v > 0.f ? v : 0.f;
        if (BF16OUT) Cb[(size_t)(rb + j) * N + col] = f2bf(v);
        else         Cf[(size_t)(rb + j) * N + col] = v;
      }
    }
  }
}

extern "C" void kernel_launch(void* const* d_in, const int* in_sizes, int n_in,
                              void* d_out, int out_size, void* d_ws, size_t ws_size,
                              hipStream_t stream) {
  const float* x   = (const float*)d_in[0];
  const float* lnw = (const float*)d_in[1];
  const float* lnb = (const float*)d_in[2];
  const float* w1  = (const float*)d_in[3];
  const float* b1  = (const float*)d_in[4];
  const float* w2  = (const float*)d_in[5];
  const float* b2  = (const float*)d_in[6];
  float* out = (float*)d_out;

  char* ws = (char*)d_ws;
  unsigned short* x_ln = (unsigned short*)(ws);                      // 16 MB
  unsigned short* w1t  = (unsigned short*)(ws + (16u << 20));        //  8 MB
  unsigned short* w2t  = (unsigned short*)(ws + (24u << 20));        //  8 MB
  unsigned short* h    = (unsigned short*)(ws + (32u << 20));        // 64 MB

  ln_bf16_kernel<<<NROWS, 256, 0, stream>>>(x, lnw, lnb, x_ln);
  transpose_f32_bf16<<<dim3(D_FF / 32, D_MODEL / 32), dim3(32, 8), 0, stream>>>(
      w1, w1t, D_MODEL, D_FF);
  transpose_f32_bf16<<<dim3(D_MODEL / 32, D_FF / 32), dim3(32, 8), 0, stream>>>(
      w2, w2t, D_FF, D_MODEL);
  // h = ReLU(x_ln @ w1 + b1), bf16.  grid 16x32 = 512 blocks, 512 thr.
  gemm8p<256, 1, 1><<<dim3(D_FF / 256, NROWS / 256), 512, 0, stream>>>(
      x_ln, w1t, b1, h, nullptr, NROWS, D_FF, D_MODEL);
  // out = h @ w2 + b2, fp32.  grid 8x32 = 256 blocks, 512 thr.
  gemm8p<128, 0, 0><<<dim3(D_MODEL / 128, NROWS / 256), 512, 0, stream>>>(
      h, w2t, b2, nullptr, out, NROWS, D_MODEL, D_FF);
}

// Round 7
// 261.075 us; speedup vs baseline: 1.1657x; 1.0629x over previous
//
#include <hip/hip_runtime.h>
#include <stdint.h>

#define D_MODEL 1024
#define D_FF    4096
#define NROWS   8192   // 4 * 2048

typedef __attribute__((ext_vector_type(4))) float f32x4;
typedef __attribute__((ext_vector_type(8))) short short8;

__device__ __forceinline__ unsigned short f2bf(float f) {
  unsigned u = __float_as_uint(f);
  u += 0x7fffu + ((u >> 16) & 1u);   // round-to-nearest-even
  return (unsigned short)(u >> 16);
}

template <int N>
__device__ __forceinline__ void wait_vmcnt() {
  asm volatile("s_waitcnt vmcnt(%0)" ::"n"(N) : "memory");
}

// ---------------- LayerNorm (fp32 in) -> bf16 out ----------------
__global__ __launch_bounds__(256) void ln_bf16_kernel(
    const float* __restrict__ x, const float* __restrict__ lnw,
    const float* __restrict__ lnb, unsigned short* __restrict__ y) {
  const int row = blockIdx.x;
  const int t = threadIdx.x;
  const int w = t >> 6, l = t & 63;
  const float4* xr = (const float4*)(x + (size_t)row * D_MODEL);
  float4 v = xr[t];
  float s  = v.x + v.y + v.z + v.w;
  float s2 = v.x * v.x + v.y * v.y + v.z * v.z + v.w * v.w;
#pragma unroll
  for (int o = 32; o >= 1; o >>= 1) {
    s  += __shfl_xor(s, o);
    s2 += __shfl_xor(s2, o);
  }
  __shared__ float red[8];
  if (l == 0) { red[w] = s; red[4 + w] = s2; }
  __syncthreads();
  s  = red[0] + red[1] + red[2] + red[3];
  s2 = red[4] + red[5] + red[6] + red[7];
  const float mu  = s * (1.0f / D_MODEL);
  const float var = s2 * (1.0f / D_MODEL) - mu * mu;
  const float rs  = rsqrtf(var + 1e-5f);
  float4 wv = ((const float4*)lnw)[t];
  float4 bv = ((const float4*)lnb)[t];
  ushort4 o4;
  o4.x = f2bf((v.x - mu) * rs * wv.x + bv.x);
  o4.y = f2bf((v.y - mu) * rs * wv.y + bv.y);
  o4.z = f2bf((v.z - mu) * rs * wv.z + bv.z);
  o4.w = f2bf((v.w - mu) * rs * wv.w + bv.w);
  *(ushort4*)(y + (size_t)row * D_MODEL + t * 4) = o4;
}

// ------------- transpose + fp32->bf16 convert: dst[C][R] = src[R][C] -------------
__global__ __launch_bounds__(256) void transpose_f32_bf16(
    const float* __restrict__ src, unsigned short* __restrict__ dst,
    int R, int C) {
  __shared__ float tile[32][33];
  const int tx = threadIdx.x;  // 0..31
  const int ty = threadIdx.y;  // 0..7
  const int r0 = blockIdx.y * 32, c0 = blockIdx.x * 32;
#pragma unroll
  for (int i = 0; i < 32; i += 8)
    tile[ty + i][tx] = src[(size_t)(r0 + ty + i) * C + (c0 + tx)];
  __syncthreads();
#pragma unroll
  for (int i = 0; i < 32; i += 8)
    dst[(size_t)(c0 + ty + i) * R + (r0 + tx)] = f2bf(tile[tx][ty + i]);
}

// ============ 8-phase 256xBN bf16 GEMM, snake order + frag persistence ============
// Same sync structure as round 6 (stage slots, waits, barriers identical; ledger
// verified: every read covered by previous phase's wait + barrier, distance>=5).
// Change: quadrant order per buffer is (0,0),(0,1),(1,1),(1,0); af loaded only on
// MQ-entry phases, each bv-half loaded once per K-tile and kept in registers.
// LDS reads drop 48->24 b128 per K-tile per wave (G1), 40->20 (G2) = unique min.
//
// Per-iteration (slot: reads buf/quad [loads] | stages region <- K-tile):
//  p0: b0 (0,0) [af,b0] | b1.B1 <- k1     p4: b1 (0,0) [af,b0] | b0.B1 <- k2
//  p1: b0 (0,1) [b1]    | b1.A1 <- k1     p5: b1 (0,1) [b1]    | b0.A1 <- k2
//  p2: b0 (1,1) [af]    | b0.A0 <- k2     p6: b1 (1,1) [af]    | b1.A0 <- k3
//  p3: b0 (1,0) []      | b0.B0 <- k2     p7: b1 (1,0) []      | b1.B0 <- k3
template <int BN, int RELU, int BF16OUT>
__global__ __launch_bounds__(512, 2) void gemm8s(
    const unsigned short* __restrict__ A, const unsigned short* __restrict__ Bt,
    const float* __restrict__ bias, unsigned short* __restrict__ Cb,
    float* __restrict__ Cf, int M, int N, int K) {
  constexpr int BM = 256;
  constexpr int FN = BN / 64;        // n-frags per wave (4 or 2)
  constexpr int FNH = FN / 2;        // n-frags per quadrant (2 or 1)
  constexpr int LA = 2;              // global_load_lds per thread per A-half
  constexpr int LB = BN / 128;       // ... per B-half (2 or 1)
  constexpr int AH = 128 * 64;       // shorts per A-half
  constexpr int BH = (BN / 2) * 64;  // shorts per B-half
  constexpr int BUFSZ = 2 * AH + 2 * BH;  // shorts per K-tile buffer
  constexpr int RPW = BN / 8;        // B rows per wave per half (32 or 16)
  constexpr int WTN = BN / 4;        // wave n-extent
  constexpr int NW_A = 2 * LA + LB;  // vmcnt at slots 0,3,4,7
  constexpr int NW_B = LA + 2 * LB;  // vmcnt at slots 1,2,5,6

  __shared__ short lds[2 * BUFSZ];

  const int t = threadIdx.x;
  const int w = t >> 6, l = t & 63;
  const int wm = w >> 2, wn = w & 3;
  const int lr = l & 15, lg = l >> 4, l7 = l & 7;
  const int wm64 = wm * 64, wnr = wn * RPW;

  // T1: XCD-chunked bijective remap (nwg % 8 == 0 for both grids).
  const int gx = gridDim.x;
  const int nwg = gx * gridDim.y;
  int id = blockIdx.y * gx + blockIdx.x;
  id = (id & 7) * (nwg >> 3) + (id >> 3);
  const int bn0 = (id % gx) * BN;
  const int bm0 = (id / gx) * BM;

  f32x4 acc[8][FN];
#pragma unroll
  for (int i = 0; i < 8; ++i)
#pragma unroll
    for (int j = 0; j < FN; ++j) acc[i][j] = (f32x4){0.f, 0.f, 0.f, 0.f};

  short8 af[2][4];        // A frags of current MQ half (persist 2 phases)
  short8 bq[2][2][FNH];   // B frags, both NQ halves (persist whole K-tile)

  // Stage A-half mq of K-tile kt into buffer buf. Linear LDS dest
  // (uniform base + lane*16); global source pre-swizzled (slot ^ row&7).
  auto stageA = [&](int buf, int mq, int kt) {
#pragma unroll
    for (int i = 0; i < LA; ++i) {
      const int idx = i * 512 + t;
      const int r = idx >> 3;                      // row within half [0,128)
      const int sl = (idx & 7) ^ (r & 7);          // source k-slot
      const int grow = bm0 + ((r >> 6) << 7) + (mq << 6) + (r & 63);
      __builtin_amdgcn_global_load_lds(
          (const __attribute__((address_space(1))) void*)(A + (size_t)grow * K + kt * 64 + sl * 8),
          (__attribute__((address_space(3))) void*)(&lds[buf * BUFSZ + mq * AH + idx * 8]),
          16, 0, 0);
    }
  };
  auto stageB = [&](int buf, int nq, int kt) {
#pragma unroll
    for (int i = 0; i < LB; ++i) {
      const int idx = i * 512 + t;
      const int r = idx >> 3;                      // row within half [0,BN/2)
      const int sl = (idx & 7) ^ (r & 7);
      const int grow = bn0 + (r / RPW) * WTN + nq * RPW + (r % RPW);
      __builtin_amdgcn_global_load_lds(
          (const __attribute__((address_space(1))) void*)(Bt + (size_t)grow * K + kt * 64 + sl * 8),
          (__attribute__((address_space(3))) void*)(&lds[buf * BUFSZ + 2 * AH + nq * BH + idx * 8]),
          16, 0, 0);
    }
  };

// One phase: counted vmcnt; optional af / bv-half ds_reads (swizzled); issue 1
// half-tile stage; barrier; lgkmcnt(0)+sched_barrier (rule 18); setprio'd MFMA
// cluster (operands may persist from earlier phases); sched_barrier; barrier.
#define PHASE(MQ, NQ, BUFR, NWAIT, LDA_, LDB_, STAGESTMT)                      \
  {                                                                            \
    wait_vmcnt<NWAIT>();                                                       \
    if (LDA_) {                                                                \
      _Pragma("unroll") for (int ks = 0; ks < 2; ++ks)                         \
        _Pragma("unroll") for (int f = 0; f < 4; ++f)                          \
          af[ks][f] = *(const short8*)&lds[(BUFR) * BUFSZ + (MQ) * AH +        \
              (wm64 + f * 16 + lr) * 64 + ((((ks << 2) | lg) ^ l7) << 3)];     \
    }                                                                          \
    if (LDB_) {                                                                \
      _Pragma("unroll") for (int ks = 0; ks < 2; ++ks)                         \
        _Pragma("unroll") for (int g = 0; g < FNH; ++g)                        \
          bq[NQ][ks][g] = *(const short8*)&lds[(BUFR) * BUFSZ + 2 * AH +       \
              (NQ) * BH + (wnr + g * 16 + lr) * 64 +                           \
              ((((ks << 2) | lg) ^ l7) << 3)];                                 \
    }                                                                          \
    STAGESTMT;                                                                 \
    __builtin_amdgcn_s_barrier();                                              \
    asm volatile("s_waitcnt lgkmcnt(0)" ::: "memory");                         \
    __builtin_amdgcn_sched_barrier(0);                                         \
    __builtin_amdgcn_s_setprio(1);                                             \
    _Pragma("unroll") for (int ks = 0; ks < 2; ++ks)                           \
      _Pragma("unroll") for (int f = 0; f < 4; ++f)                            \
        _Pragma("unroll") for (int g = 0; g < FNH; ++g)                        \
          acc[(MQ) * 4 + f][(NQ) * FNH + g] =                                  \
              __builtin_amdgcn_mfma_f32_16x16x32_bf16(                         \
                  af[ks][f], bq[NQ][ks][g], acc[(MQ) * 4 + f][(NQ) * FNH + g], \
                  0, 0, 0);                                                    \
    __builtin_amdgcn_s_setprio(0);                                             \
    __builtin_amdgcn_sched_barrier(0);                                         \
    __builtin_amdgcn_s_barrier();                                              \
  }

  const int KT_MAX = (K >> 6) - 1;
  const int NIT = K >> 7;

  // Prologue: buf0 K-tile 0 (A0,B0,B1,A1) + buf1 K-tile 1 (A0,B0).
  stageA(0, 0, 0);
  stageB(0, 0, 0);
  stageB(0, 1, 0);
  stageA(0, 1, 0);
  stageA(1, 0, 1);
  stageB(1, 0, 1);
  wait_vmcnt<2 * LA + 2 * LB>();   // A0,B0 of buf0 landed (all waves at barrier)
  __builtin_amdgcn_s_barrier();

  for (int it = 0; it < NIT; ++it) {
    const int k1 = 2 * it + 1;
    int k2 = 2 * it + 2; k2 = k2 > KT_MAX ? KT_MAX : k2;
    int k3 = 2 * it + 3; k3 = k3 > KT_MAX ? KT_MAX : k3;
    PHASE(0, 0, 0, NW_A, 1, 1, stageB(1, 1, k1));   // af<-A0, bq0<-B0
    PHASE(0, 1, 0, NW_B, 0, 1, stageA(1, 1, k1));   // bq1<-B1 (af kept)
    PHASE(1, 1, 0, NW_B, 1, 0, stageA(0, 0, k2));   // af<-A1 (bq1 kept)
    PHASE(1, 0, 0, NW_A, 0, 0, stageB(0, 0, k2));   // all kept
    PHASE(0, 0, 1, NW_A, 1, 1, stageB(0, 1, k2));
    PHASE(0, 1, 1, NW_B, 0, 1, stageA(0, 1, k2));
    PHASE(1, 1, 1, NW_B, 1, 0, stageA(1, 0, k3));
    PHASE(1, 0, 1, NW_A, 0, 0, stageB(1, 0, k3));
  }
#undef PHASE
  asm volatile("s_waitcnt vmcnt(0)" ::: "memory");  // drain tail stages

  // Epilogue: D(m,n): col = lane&15, row = (lane>>4)*4 + reg (verified layout)
#pragma unroll
  for (int fn = 0; fn < FN; ++fn) {
    const int col = bn0 + wn * WTN + fn * 16 + lr;
    const float bvs = bias[col];
#pragma unroll
    for (int fm = 0; fm < 8; ++fm) {
      const int rb = bm0 + wm * 128 + fm * 16 + lg * 4;
#pragma unroll
      for (int j = 0; j < 4; ++j) {
        float v = acc[fm][fn][j] + bvs;
        if (RELU) v = v > 0.f ? v : 0.f;
        if (BF16OUT) Cb[(size_t)(rb + j) * N + col] = f2bf(v);
        else         Cf[(size_t)(rb + j) * N + col] = v;
      }
    }
  }
}

extern "C" void kernel_launch(void* const* d_in, const int* in_sizes, int n_in,
                              void* d_out, int out_size, void* d_ws, size_t ws_size,
                              hipStream_t stream) {
  const float* x   = (const float*)d_in[0];
  const float* lnw = (const float*)d_in[1];
  const float* lnb = (const float*)d_in[2];
  const float* w1  = (const float*)d_in[3];
  const float* b1  = (const float*)d_in[4];
  const float* w2  = (const float*)d_in[5];
  const float* b2  = (const float*)d_in[6];
  float* out = (float*)d_out;

  char* ws = (char*)d_ws;
  unsigned short* x_ln = (unsigned short*)(ws);                      // 16 MB
  unsigned short* w1t  = (unsigned short*)(ws + (16u << 20));        //  8 MB
  unsigned short* w2t  = (unsigned short*)(ws + (24u << 20));        //  8 MB
  unsigned short* h    = (unsigned short*)(ws + (32u << 20));        // 64 MB

  ln_bf16_kernel<<<NROWS, 256, 0, stream>>>(x, lnw, lnb, x_ln);
  transpose_f32_bf16<<<dim3(D_FF / 32, D_MODEL / 32), dim3(32, 8), 0, stream>>>(
      w1, w1t, D_MODEL, D_FF);
  transpose_f32_bf16<<<dim3(D_MODEL / 32, D_FF / 32), dim3(32, 8), 0, stream>>>(
      w2, w2t, D_FF, D_MODEL);
  // h = ReLU(x_ln @ w1 + b1), bf16.  grid 16x32 = 512 blocks, 512 thr.
  gemm8s<256, 1, 1><<<dim3(D_FF / 256, NROWS / 256), 512, 0, stream>>>(
      x_ln, w1t, b1, h, nullptr, NROWS, D_FF, D_MODEL);
  // out = h @ w2 + b2, fp32.  grid 8x32 = 256 blocks, 512 thr.
  gemm8s<128, 0, 0><<<dim3(D_MODEL / 128, NROWS / 256), 512, 0, stream>>>(
      h, w2t, b2, nullptr, out, NROWS, D_MODEL, D_FF);
}

// Round 8
// 249.018 us; speedup vs baseline: 1.2222x; 1.0484x over previous
//
#include <hip/hip_runtime.h>
#include <stdint.h>

#define D_MODEL 1024
#define D_FF    4096
#define NROWS   8192   // 4 * 2048

typedef __attribute__((ext_vector_type(4))) float f32x4;
typedef __attribute__((ext_vector_type(8))) short short8;

__device__ __forceinline__ unsigned short f2bf(float f) {
  unsigned u = __float_as_uint(f);
  u += 0x7fffu + ((u >> 16) & 1u);   // round-to-nearest-even
  return (unsigned short)(u >> 16);
}

template <int N>
__device__ __forceinline__ void wait_vmcnt() {
  asm volatile("s_waitcnt vmcnt(%0)" ::"n"(N) : "memory");
}

// ---------------- LayerNorm (fp32 in) -> bf16 out ----------------
__global__ __launch_bounds__(256) void ln_bf16_kernel(
    const float* __restrict__ x, const float* __restrict__ lnw,
    const float* __restrict__ lnb, unsigned short* __restrict__ y) {
  const int row = blockIdx.x;
  const int t = threadIdx.x;
  const int w = t >> 6, l = t & 63;
  const float4* xr = (const float4*)(x + (size_t)row * D_MODEL);
  float4 v = xr[t];
  float s  = v.x + v.y + v.z + v.w;
  float s2 = v.x * v.x + v.y * v.y + v.z * v.z + v.w * v.w;
#pragma unroll
  for (int o = 32; o >= 1; o >>= 1) {
    s  += __shfl_xor(s, o);
    s2 += __shfl_xor(s2, o);
  }
  __shared__ float red[8];
  if (l == 0) { red[w] = s; red[4 + w] = s2; }
  __syncthreads();
  s  = red[0] + red[1] + red[2] + red[3];
  s2 = red[4] + red[5] + red[6] + red[7];
  const float mu  = s * (1.0f / D_MODEL);
  const float var = s2 * (1.0f / D_MODEL) - mu * mu;
  const float rs  = rsqrtf(var + 1e-5f);
  float4 wv = ((const float4*)lnw)[t];
  float4 bv = ((const float4*)lnb)[t];
  ushort4 o4;
  o4.x = f2bf((v.x - mu) * rs * wv.x + bv.x);
  o4.y = f2bf((v.y - mu) * rs * wv.y + bv.y);
  o4.z = f2bf((v.z - mu) * rs * wv.z + bv.z);
  o4.w = f2bf((v.w - mu) * rs * wv.w + bv.w);
  *(ushort4*)(y + (size_t)row * D_MODEL + t * 4) = o4;
}

// ------------- transpose + fp32->bf16 convert: dst[C][R] = src[R][C] -------------
__global__ __launch_bounds__(256) void transpose_f32_bf16(
    const float* __restrict__ src, unsigned short* __restrict__ dst,
    int R, int C) {
  __shared__ float tile[32][33];
  const int tx = threadIdx.x;  // 0..31
  const int ty = threadIdx.y;  // 0..7
  const int r0 = blockIdx.y * 32, c0 = blockIdx.x * 32;
#pragma unroll
  for (int i = 0; i < 32; i += 8)
    tile[ty + i][tx] = src[(size_t)(r0 + ty + i) * C + (c0 + tx)];
  __syncthreads();
#pragma unroll
  for (int i = 0; i < 32; i += 8)
    dst[(size_t)(c0 + ty + i) * R + (r0 + tx)] = f2bf(tile[tx][ty + i]);
}

// ============ 8-phase 256xBN bf16 GEMM — precomputed addrs, balanced reads ============
// Sync skeleton = round 6/7 (verified): same stage slots, same counted vmcnt per
// slot, 2 barriers/phase. Changes: compile-time M/N/K; per-thread global/LDS
// offsets precomputed once; no lgkmcnt(0)/sched_barrier (plain-C++ ds_reads ->
// compiler emits progressive lgkmcnt); reads balanced {8,4,8,4} via statically
// double-buffered B0 frags (bq0e for buf0, bq0o for buf1), B0 prefetched one
// phase early (distance-4, ledger-verified: governing wait retires it).
//   p0: af<-b0.A0 (B=bq0e)  | stB(1,1,k1)   p4: af<-b1.A0 (B=bq0o) | stB(0,1,k2)
//   p1: bq1<-b0.B1          | stA(1,1,k1)   p5: bq1<-b1.B1         | stA(0,1,k2)
//   p2: af<-b0.A1 (B=bq1)   | stA(0,0,k2)   p6: af<-b1.A1 (B=bq1)  | stA(1,0,k3)
//   p3: bq0o<-b1.B0 (B=bq0e)| stB(0,0,k2)   p7: bq0e<-b0.B0 (B=bq0o)| stB(1,0,k3)
template <int BN, int N_, int K_, int RELU, int BF16OUT>
__global__ __launch_bounds__(512, 2) void gemm8s(
    const unsigned short* __restrict__ A, const unsigned short* __restrict__ Bt,
    const float* __restrict__ bias, unsigned short* __restrict__ Cb,
    float* __restrict__ Cf) {
  constexpr int FN = BN / 64;        // n-frags per wave (4 or 2)
  constexpr int FNH = FN / 2;        // n-frags per quadrant (2 or 1)
  constexpr int LA = 2;              // global_load_lds per thread per A-half
  constexpr int LB = BN / 128;       // ... per B-half (2 or 1)
  constexpr int AH = 128 * 64;       // shorts per A-half
  constexpr int BH = (BN / 2) * 64;  // shorts per B-half
  constexpr int BUFSZ = 2 * AH + 2 * BH;
  constexpr int RPW = BN / 8;        // B rows per wave per half
  constexpr int WTN = BN / 4;        // wave n-extent
  constexpr int NW_A = 2 * LA + LB;  // vmcnt at slots 0,3,4,7
  constexpr int NW_B = LA + 2 * LB;  // vmcnt at slots 1,2,5,6

  __shared__ short lds[2 * BUFSZ];
  char* const ldsc = (char*)lds;

  const int t = threadIdx.x;
  const int w = t >> 6, l = t & 63;
  const int wm = w >> 2, wn = w & 3;
  const int lr = l & 15, lg = l >> 4, l7 = l & 7;
  const int wm64 = wm * 64, wnr = wn * RPW;

  // T1: XCD-chunked bijective remap (nwg % 8 == 0 for both grids).
  const int gx = gridDim.x;
  const int nwg = gx * gridDim.y;
  int id = blockIdx.y * gx + blockIdx.x;
  id = (id & 7) * (nwg >> 3) + (id >> 3);
  const int bn0 = (id % gx) * BN;
  const int bm0 = (id / gx) * BN == 0 ? (id / gx) * 256 : (id / gx) * 256;  // BM=256

  // ---- precomputed per-thread stage addresses (global) and LDS offsets ----
  const unsigned short* ApB[LA];   // A source base (mq=0, kt=0)
  int lwA[LA];                     // LDS dest short-offset within (buf=0,mq=0)
#pragma unroll
  for (int i = 0; i < LA; ++i) {
    const int idx = i * 512 + t;
    const int r = idx >> 3;
    const int sl = (idx & 7) ^ (r & 7);
    ApB[i] = A + (size_t)(bm0 + ((r >> 6) << 7) + (r & 63)) * K_ + (sl << 3);
    lwA[i] = idx * 8;
  }
  const unsigned short* BpB[LB];
  int lwB[LB];
#pragma unroll
  for (int i = 0; i < LB; ++i) {
    const int idx = i * 512 + t;
    const int r = idx >> 3;
    const int sl = (idx & 7) ^ (r & 7);
    BpB[i] = Bt + (size_t)(bn0 + (r / RPW) * WTN + (r % RPW)) * K_ + (sl << 3);
    lwB[i] = idx * 8;
  }
  // ds_read byte offsets (within a half region), swizzle folded in.
  int aok[2][4], bok[2][FNH];
#pragma unroll
  for (int ks = 0; ks < 2; ++ks) {
    const int ko = (((ks << 2) | lg) ^ l7) << 3;
#pragma unroll
    for (int f = 0; f < 4; ++f) aok[ks][f] = ((wm64 + f * 16 + lr) * 64 + ko) * 2;
#pragma unroll
    for (int g = 0; g < FNH; ++g) bok[ks][g] = ((wnr + g * 16 + lr) * 64 + ko) * 2;
  }

  f32x4 acc[8][FN];
#pragma unroll
  for (int i = 0; i < 8; ++i)
#pragma unroll
    for (int j = 0; j < FN; ++j) acc[i][j] = (f32x4){0.f, 0.f, 0.f, 0.f};

  short8 af[2][4];        // A frags of current MQ half
  short8 bq1[2][FNH];     // B1 frags (loaded and used within 2 phases)
  short8 bq0e[2][FNH];    // B0 frags for buf0 quadrants
  short8 bq0o[2][FNH];    // B0 frags for buf1 quadrants

  auto stageA = [&](int buf, int mq, int kt) {
#pragma unroll
    for (int i = 0; i < LA; ++i)
      __builtin_amdgcn_global_load_lds(
          (const __attribute__((address_space(1))) void*)(ApB[i] + mq * (64 * K_) + kt * 64),
          (__attribute__((address_space(3))) void*)(&lds[buf * BUFSZ + mq * AH + lwA[i]]),
          16, 0, 0);
  };
  auto stageB = [&](int buf, int nq, int kt) {
#pragma unroll
    for (int i = 0; i < LB; ++i)
      __builtin_amdgcn_global_load_lds(
          (const __attribute__((address_space(1))) void*)(BpB[i] + nq * (RPW * K_) + kt * 64),
          (__attribute__((address_space(3))) void*)(&lds[buf * BUFSZ + 2 * AH + nq * BH + lwB[i]]),
          16, 0, 0);
  };

// RDA: load af from buf/mq; RDB: load a B-frag set from buf/nq.
#define RDA(BUFR, MQ)                                                          \
  _Pragma("unroll") for (int ks = 0; ks < 2; ++ks)                             \
    _Pragma("unroll") for (int f = 0; f < 4; ++f)                              \
      af[ks][f] = *(const short8*)(ldsc + ((BUFR) * BUFSZ + (MQ) * AH) * 2 +   \
                                   aok[ks][f]);
#define RDB(DST, BUFR, NQ)                                                     \
  _Pragma("unroll") for (int ks = 0; ks < 2; ++ks)                             \
    _Pragma("unroll") for (int g = 0; g < FNH; ++g)                            \
      DST[ks][g] = *(const short8*)(ldsc + ((BUFR) * BUFSZ + 2 * AH +          \
                                            (NQ) * BH) * 2 + bok[ks][g]);
// One phase: counted vmcnt; reads; stage; barrier; MFMA (compiler-managed
// progressive lgkmcnt); barrier.
#define PHASE(MQ, NQ, BOP, NWAIT, RDSTMT, STAGESTMT)                           \
  {                                                                            \
    wait_vmcnt<NWAIT>();                                                       \
    RDSTMT;                                                                    \
    STAGESTMT;                                                                 \
    __builtin_amdgcn_s_barrier();                                              \
    __builtin_amdgcn_s_setprio(1);                                             \
    _Pragma("unroll") for (int ks = 0; ks < 2; ++ks)                           \
      _Pragma("unroll") for (int f = 0; f < 4; ++f)                            \
        _Pragma("unroll") for (int g = 0; g < FNH; ++g)                        \
          acc[(MQ) * 4 + f][(NQ) * FNH + g] =                                  \
              __builtin_amdgcn_mfma_f32_16x16x32_bf16(                         \
                  af[ks][f], BOP[ks][g], acc[(MQ) * 4 + f][(NQ) * FNH + g],    \
                  0, 0, 0);                                                    \
    __builtin_amdgcn_s_setprio(0);                                             \
    __builtin_amdgcn_s_barrier();                                              \
  }

  constexpr int KT_MAX = (K_ >> 6) - 1;
  constexpr int NIT = K_ >> 7;

  // Prologue: buf0 K-tile 0 (A0,B0,B1,A1) + buf1 K-tile 1 (A0,B0).
  stageA(0, 0, 0);
  stageB(0, 0, 0);
  stageB(0, 1, 0);
  stageA(0, 1, 0);
  stageA(1, 0, 1);
  stageB(1, 0, 1);
  wait_vmcnt<2 * LA + 2 * LB>();   // A0,B0 of buf0 landed
  __builtin_amdgcn_s_barrier();
  RDB(bq0e, 0, 0);                 // B0 frags of K-tile 0

  for (int it = 0; it < NIT; ++it) {
    const int k1 = 2 * it + 1;
    int k2 = 2 * it + 2; k2 = k2 > KT_MAX ? KT_MAX : k2;
    int k3 = 2 * it + 3; k3 = k3 > KT_MAX ? KT_MAX : k3;
    PHASE(0, 0, bq0e, NW_A, RDA(0, 0),      stageB(1, 1, k1));
    PHASE(0, 1, bq1,  NW_B, RDB(bq1, 0, 1), stageA(1, 1, k1));
    PHASE(1, 1, bq1,  NW_B, RDA(0, 1),      stageA(0, 0, k2));
    PHASE(1, 0, bq0e, NW_A, RDB(bq0o, 1, 0), stageB(0, 0, k2));
    PHASE(0, 0, bq0o, NW_A, RDA(1, 0),      stageB(0, 1, k2));
    PHASE(0, 1, bq1,  NW_B, RDB(bq1, 1, 1), stageA(0, 1, k2));
    PHASE(1, 1, bq1,  NW_B, RDA(1, 1),      stageA(1, 0, k3));
    PHASE(1, 0, bq0o, NW_A, RDB(bq0e, 0, 0), stageB(1, 0, k3));
  }
#undef PHASE
#undef RDA
#undef RDB
  asm volatile("s_waitcnt vmcnt(0)" ::: "memory");  // drain tail stages

  if (BF16OUT) {
    // LDS-bounce epilogue: 8 slices of 32 rows x BN cols; vectorized 16B stores.
    constexpr int SLP = BN + 16;     // padded row stride (shorts)
    constexpr int TPR = BN / 8;      // threads per row on readback
    constexpr int RPR = 512 / TPR;   // rows per readback round
    float bvs[FN];
#pragma unroll
    for (int fn = 0; fn < FN; ++fn) bvs[fn] = bias[bn0 + wn * WTN + fn * 16 + lr];
#pragma unroll
    for (int fm = 0; fm < 8; ++fm) {
      __syncthreads();
#pragma unroll
      for (int fn = 0; fn < FN; ++fn) {
        const int scol = wn * WTN + fn * 16 + lr;
#pragma unroll
        for (int j = 0; j < 4; ++j) {
          float v = acc[fm][fn][j] + bvs[fn];
          if (RELU) v = v > 0.f ? v : 0.f;
          lds[(wm * 16 + lg * 4 + j) * SLP + scol] = (short)f2bf(v);
        }
      }
      __syncthreads();
#pragma unroll
      for (int rnd = 0; rnd < 32 / RPR; ++rnd) {
        const int ri = t / TPR + rnd * RPR;
        const int ci = (t % TPR) * 8;
        const int gr = bm0 + ((ri >> 4) << 7) + fm * 16 + (ri & 15);
        *(short8*)&Cb[(size_t)gr * N_ + bn0 + ci] = *(const short8*)&lds[ri * SLP + ci];
      }
    }
  } else {
    // Direct f32 stores (full 64B lines per 16-lane group).
#pragma unroll
    for (int fn = 0; fn < FN; ++fn) {
      const int col = bn0 + wn * WTN + fn * 16 + lr;
      const float bvs = bias[col];
#pragma unroll
      for (int fm = 0; fm < 8; ++fm) {
        const int rb = bm0 + wm * 128 + fm * 16 + lg * 4;
#pragma unroll
        for (int j = 0; j < 4; ++j) {
          float v = acc[fm][fn][j] + bvs;
          if (RELU) v = v > 0.f ? v : 0.f;
          Cf[(size_t)(rb + j) * N_ + col] = v;
        }
      }
    }
  }
}

extern "C" void kernel_launch(void* const* d_in, const int* in_sizes, int n_in,
                              void* d_out, int out_size, void* d_ws, size_t ws_size,
                              hipStream_t stream) {
  const float* x   = (const float*)d_in[0];
  const float* lnw = (const float*)d_in[1];
  const float* lnb = (const float*)d_in[2];
  const float* w1  = (const float*)d_in[3];
  const float* b1  = (const float*)d_in[4];
  const float* w2  = (const float*)d_in[5];
  const float* b2  = (const float*)d_in[6];
  float* out = (float*)d_out;

  char* ws = (char*)d_ws;
  unsigned short* x_ln = (unsigned short*)(ws);                      // 16 MB
  unsigned short* w1t  = (unsigned short*)(ws + (16u << 20));        //  8 MB
  unsigned short* w2t  = (unsigned short*)(ws + (24u << 20));        //  8 MB
  unsigned short* h    = (unsigned short*)(ws + (32u << 20));        // 64 MB

  ln_bf16_kernel<<<NROWS, 256, 0, stream>>>(x, lnw, lnb, x_ln);
  transpose_f32_bf16<<<dim3(D_FF / 32, D_MODEL / 32), dim3(32, 8), 0, stream>>>(
      w1, w1t, D_MODEL, D_FF);
  transpose_f32_bf16<<<dim3(D_MODEL / 32, D_FF / 32), dim3(32, 8), 0, stream>>>(
      w2, w2t, D_FF, D_MODEL);
  // h = ReLU(x_ln @ w1 + b1), bf16.  grid 16x32 = 512 blocks, 512 thr.
  gemm8s<256, D_FF, D_MODEL, 1, 1><<<dim3(D_FF / 256, NROWS / 256), 512, 0, stream>>>(
      x_ln, w1t, b1, h, nullptr);
  // out = h @ w2 + b2, fp32.  grid 8x32 = 256 blocks, 512 thr.
  gemm8s<128, D_MODEL, D_FF, 0, 0><<<dim3(D_MODEL / 128, NROWS / 256), 512, 0, stream>>>(
      h, w2t, b2, nullptr, out);
}